// Round 6
// baseline (15819.119 us; speedup 1.0000x reference)
//
#include <hip/hip_runtime.h>
#include <cmath>

// VanillaRNN persistent kernel (R8): R0's proven flag protocol, shortened.
// h_{t+1} = tanh(U[:,x_t] + W h_t + bh);  y_t = V h_{t+1} + by.
// 256 WGs = 16 row-blocks (32 rows of H) x 16 col-groups (16 cols of B).
// W,V in registers as split-bf16 MFMA fragments (loaded once).
// Sync = R0's acquire/release flags (the ONLY mechanism that has passed:
// R3/R5/R7's data-word polling failed deterministically at 1.16e-2 thrice).
// R8 deltas vs R0, none touching memory-visibility semantics:
//  1. all-lane flag poll + per-thread ACQUIRE (removes tid0-spin->syncthreads)
//  2. xs/U gather hoisted above the wait (latency hidden under poll)
//  3. early release: waves 0,1 wave-drain their h stores (s_waitcnt vmcnt(0)
//     is wave-wide) and lane0 of each does RELEASE fetch_add(+1) -> flag
//     target 32; y finalize + its out-store drain moved off the critical path
//  4. poll bounded (deadlock -> visible error, not a hang)

typedef __attribute__((ext_vector_type(8))) short short8;
typedef __attribute__((ext_vector_type(4))) float f32x4;

namespace {
constexpr int T_ = 1024, B_ = 256, D_ = 256, H_ = 512, O_ = 256;
constexpr int NPROD = 32;        // producers per flag: 16 row-blocks x 2 waves
constexpr int HB = H_ * B_;      // 131072 floats
constexpr int HSP = 520;         // padded k-stride (shorts) for staged h
constexpr int POLL_BOUND = 4096; // ~100us of s_sleep(1) retries
}

__device__ __forceinline__ short bf16_rne(float x) {
  unsigned u = __float_as_uint(x);
  unsigned r = u + 0x7FFFu + ((u >> 16) & 1u);
  return (short)(r >> 16);
}
__device__ __forceinline__ float bf16_to_f(short h) {
  return __uint_as_float(((unsigned)(unsigned short)h) << 16);
}

__global__ void rnn_init(const float* __restrict__ h0, float* __restrict__ hbuf,
                         int* __restrict__ flags) {
  const int idx = blockIdx.x * 256 + threadIdx.x;  // grid 128*256 = 32768
  ((f32x4*)hbuf)[idx] = ((const f32x4*)h0)[idx];   // h0 -> buf0 (131072 f32)
  if (idx < 16 * (T_ + 1)) flags[idx] = 0;
}

__global__ __launch_bounds__(256, 1) void rnn_persist(
    const int* __restrict__ xs, const float* __restrict__ U,
    const float* __restrict__ W, const float* __restrict__ V,
    const float* __restrict__ bh, const float* __restrict__ by,
    float* __restrict__ out, float* __restrict__ hbuf, int* __restrict__ flags) {
  const int tid = threadIdx.x;
  const int wg = blockIdx.x;        // 0..255
  const int c = wg & 15;            // col group
  const int r = wg >> 4;            // row block
  const int Ri = r * 32;
  const int Cb = c * 16;
  const int wid = tid >> 6;         // wave 0..3
  const int l = tid & 63;
  const int lm = l & 15;            // MFMA m/n lane index
  const int lq = l >> 4;            // MFMA quad

  const int mh = wid & 1;           // h-GEMM row-half (rows 16*mh..+16)
  const int kh = wid >> 1;          // h-GEMM K-half (256 each)

  __shared__ short hs_hi[16][HSP];  // staged h_t, transposed [col][k], bf16 hi
  __shared__ short hs_lo[16][HSP];  // bf16 residual
  __shared__ float redh[2][16][17];
  __shared__ float redy[3][16][17];
  __shared__ float ytile[16][20];

  // ---- Preload weight fragments (registers, once) ----
  // A-frag layout (verified): A[m=lane&15][k=quad*8+j].
  short8 whi[8], wlo[8];
  {
    const float* p0 = W + (size_t)(Ri + 16 * mh + lm) * H_ + kh * 256 + lq * 8;
#pragma unroll
    for (int kk = 0; kk < 8; ++kk) {
      const float* p = p0 + kk * 32;
      short8 a, b;
#pragma unroll
      for (int j = 0; j < 8; ++j) {
        float x = p[j];
        short hi = bf16_rne(x);
        a[j] = hi;
        b[j] = bf16_rne(x - bf16_to_f(hi));
      }
      whi[kk] = a; wlo[kk] = b;
    }
  }
  short8 vhi[4], vlo[4];
  {
    const float* p0 = V + (size_t)(16 * r + lm) * H_ + wid * 128 + lq * 8;
#pragma unroll
    for (int kk = 0; kk < 4; ++kk) {
      const float* p = p0 + kk * 32;
      short8 a, b;
#pragma unroll
      for (int j = 0; j < 8; ++j) {
        float x = p[j];
        short hi = bf16_rne(x);
        a[j] = hi;
        b[j] = bf16_rne(x - bf16_to_f(hi));
      }
      vhi[kk] = a; vlo[kk] = b;
    }
  }
  float bhv[4], byv[4];
#pragma unroll
  for (int p = 0; p < 4; ++p) {
    bhv[p] = bh[Ri + 16 * mh + lq * 4 + p];   // used by waves 0,1 (kh==0)
    byv[p] = by[16 * r + lq * 4 + p];         // used by wave 2
  }

  const int scol = tid & 15;
  const int sk0 = (tid >> 4) * 32;

  for (int t = 0; t <= T_; ++t) {
    // ---- 1. t-only loads issued BEFORE the wait (latency hidden) ----
    float uv[4];
    if (wid < 2 && t < T_) {
      const int xv = xs[(size_t)t * B_ + Cb + lm];
#pragma unroll
      for (int p = 0; p < 4; ++p)
        uv[p] = U[(size_t)(Ri + 16 * mh + lq * 4 + p) * D_ + xv];
    }

    // ---- 2. all-lane wait for h_t complete (32 producers), own ACQUIRE ----
    if (t > 0) {
      int* f = &flags[c * (T_ + 1) + t];
      int spins = 0;
      while (__hip_atomic_load(f, __ATOMIC_RELAXED, __HIP_MEMORY_SCOPE_AGENT) <
             NPROD) {
        if (++spins > POLL_BOUND) break;  // deadlock -> visible error
        __builtin_amdgcn_s_sleep(1);
      }
      (void)__hip_atomic_load(f, __ATOMIC_ACQUIRE, __HIP_MEMORY_SCOPE_AGENT);
    }
    const float* hsrc = hbuf + (size_t)(t & 1) * HB;

    // ---- 3. stage h_t -> LDS transposed split-bf16 (plain loads, as R0) ----
    {
      const float* hp = hsrc + Cb + scol;
      float hv[32];
#pragma unroll
      for (int i = 0; i < 32; ++i) hv[i] = hp[(size_t)(sk0 + i) * B_];
      short hhi[32], hlo[32];
#pragma unroll
      for (int i = 0; i < 32; ++i) {
        short hi = bf16_rne(hv[i]);
        hhi[i] = hi;
        hlo[i] = bf16_rne(hv[i] - bf16_to_f(hi));
      }
#pragma unroll
      for (int g = 0; g < 4; ++g) {
        short8 a, b;
#pragma unroll
        for (int j = 0; j < 8; ++j) { a[j] = hhi[8 * g + j]; b[j] = hlo[8 * g + j]; }
        *(short8*)&hs_hi[scol][sk0 + 8 * g] = a;
        *(short8*)&hs_lo[scol][sk0 + 8 * g] = b;
      }
    }
    __syncthreads();

    // ---- 4. partial MFMAs (split-bf16 3-pass), exactly R0 ----
    f32x4 acc_h = {0.f, 0.f, 0.f, 0.f};
    if (t < T_) {
#pragma unroll
      for (int kk = 0; kk < 8; ++kk) {
        const int k0 = kh * 256 + kk * 32 + lq * 8;
        short8 bhi8 = *(const short8*)&hs_hi[lm][k0];
        short8 blo8 = *(const short8*)&hs_lo[lm][k0];
        acc_h = __builtin_amdgcn_mfma_f32_16x16x32_bf16(whi[kk], bhi8, acc_h, 0, 0, 0);
        acc_h = __builtin_amdgcn_mfma_f32_16x16x32_bf16(wlo[kk], bhi8, acc_h, 0, 0, 0);
        acc_h = __builtin_amdgcn_mfma_f32_16x16x32_bf16(whi[kk], blo8, acc_h, 0, 0, 0);
      }
    }
    f32x4 acc_y = {0.f, 0.f, 0.f, 0.f};
    if (t >= 1) {
#pragma unroll
      for (int kk = 0; kk < 4; ++kk) {
        const int k0 = wid * 128 + kk * 32 + lq * 8;
        short8 bhi8 = *(const short8*)&hs_hi[lm][k0];
        short8 blo8 = *(const short8*)&hs_lo[lm][k0];
        acc_y = __builtin_amdgcn_mfma_f32_16x16x32_bf16(vhi[kk], bhi8, acc_y, 0, 0, 0);
        acc_y = __builtin_amdgcn_mfma_f32_16x16x32_bf16(vlo[kk], bhi8, acc_y, 0, 0, 0);
        acc_y = __builtin_amdgcn_mfma_f32_16x16x32_bf16(vhi[kk], blo8, acc_y, 0, 0, 0);
      }
    }

    // ---- 5. cross-wave K reductions via LDS ----
    if (t < T_ && kh == 1) {
#pragma unroll
      for (int p = 0; p < 4; ++p) redh[mh][lq * 4 + p][lm] = acc_h[p];
    }
    if (t >= 1 && wid != 2) {
      const int slot = (wid < 2) ? wid : 2;  // waves 0,1,3 -> 0,1,2
#pragma unroll
      for (int p = 0; p < 4; ++p) redy[slot][lq * 4 + p][lm] = acc_y[p];
    }
    __syncthreads();

    // ---- 6a. waves 0,1: h_{t+1}, then EARLY release ----
    if (t < T_ && kh == 0) {
      float* hdst = hbuf + (size_t)((t + 1) & 1) * HB;
#pragma unroll
      for (int p = 0; p < 4; ++p) {
        const int row = lq * 4 + p;
        float pre = acc_h[p] + redh[mh][row][lm] + uv[p] + bhv[p];
        float hvv = tanhf(pre);
        const int i = Ri + 16 * mh + row;
        // write-through agent store: no dirty L2 lines to lose/flush
        __hip_atomic_store(&hdst[(size_t)i * B_ + Cb + lm], hvv,
                           __ATOMIC_RELAXED, __HIP_MEMORY_SCOPE_AGENT);
        if (t == T_ - 1)
          __builtin_nontemporal_store(
              hvv, &out[(size_t)T_ * B_ * O_ + (size_t)i * B_ + Cb + lm]);
      }
      // wave-wide drain of this wave's h stores, then per-wave release (+1).
      asm volatile("s_waitcnt vmcnt(0)" ::: "memory");
      if (l == 0)
        __hip_atomic_fetch_add(&flags[c * (T_ + 1) + t + 1], 1,
                               __ATOMIC_RELEASE, __HIP_MEMORY_SCOPE_AGENT);
    }

    // ---- 6b. wave 2: y_{t-1} (off the inter-WG critical path) ----
    if (t >= 1 && wid == 2) {
#pragma unroll
      for (int p = 0; p < 4; ++p) {
        const int row = lq * 4 + p;
        float yv = acc_y[p] + redy[0][row][lm] + redy[1][row][lm] +
                   redy[2][row][lm] + byv[p];
        ytile[lm][row] = yv;  // transposed write [b][o]
      }
      // intra-wave LDS transpose read
      const int bb = l >> 2, oj = l & 3;
      f32x4 yo = *(const f32x4*)&ytile[bb][oj * 4];
      __builtin_nontemporal_store(
          yo, (f32x4*)&out[(size_t)(t - 1) * B_ * O_ + (size_t)(Cb + bb) * O_ +
                           16 * r + oj * 4]);
    }
    __syncthreads();  // protects hs/redh/redy/ytile reuse (post-release now)
  }
}

extern "C" void kernel_launch(void* const* d_in, const int* in_sizes, int n_in,
                              void* d_out, int out_size, void* d_ws, size_t ws_size,
                              hipStream_t stream) {
  (void)in_sizes; (void)n_in; (void)out_size; (void)ws_size;
  const int* xs = (const int*)d_in[0];
  const float* h0 = (const float*)d_in[1];
  const float* U  = (const float*)d_in[2];
  const float* W  = (const float*)d_in[3];
  const float* V  = (const float*)d_in[4];
  const float* bh = (const float*)d_in[5];
  const float* by = (const float*)d_in[6];
  float* out = (float*)d_out;

  float* hbuf = (float*)d_ws;                       // 2*HB floats = 1 MiB
  int* flags = (int*)((char*)d_ws + (size_t)2 * HB * 4);  // 16*1025 ints

  rnn_init<<<128, 256, 0, stream>>>(h0, hbuf, flags);

  void* args[] = {(void*)&xs, (void*)&U, (void*)&W, (void*)&V, (void*)&bh,
                  (void*)&by, (void*)&out, (void*)&hbuf, (void*)&flags};
  (void)hipLaunchCooperativeKernel((void*)rnn_persist, dim3(256), dim3(256),
                                   args, 0, stream);
}